// Round 6
// baseline (202.283 us; speedup 1.0000x reference)
//
#include <hip/hip_runtime.h>

// out[b,a,c,k] = exp(-2*pi^2*(e_a-e_c)^2) * cos(2*pi*(m_a-m_c)) + diag noise
// Symmetric in (a,c): compute only tiles ti<=tj, mirror-store via LDS.
// Tile = 64x64 triples. lane = column, row = wave-uniform (q + 4*it).
// Stores: wave-contiguous 768B dwordx3 (R4's proven pattern).
// LDS pitch 195 (odd): both write (stride 3) and transposed read (stride
// 195 == 3 mod 32) are 2-way bank aliasing = free.

static constexpr float KNEG2 = -28.4776592f; // -2*pi^2 * log2(e)
#define TILE 64
#define LDSP 195

__device__ __forceinline__ float smk_elem(float ea, float ec, float ma, float mc) {
    const float t  = ea - ec;
    const float ex = __builtin_amdgcn_exp2f(t * t * KNEG2);
    const float u  = ma - mc;
    const float cs = __builtin_amdgcn_cosf(__builtin_amdgcn_fractf(u));
    return ex * cs;
}

__global__ __launch_bounds__(256) void smk_sym(
    const float* __restrict__ xc,      // (nb*n, 3)
    const float* __restrict__ mu,      // (3,)
    const float* __restrict__ inv_std, // (3,)
    const float* __restrict__ likerr,  // (3,)
    float* __restrict__ out,           // (nb*n, n*3)
    int n, int S, int U)
{
    __shared__ float V[TILE * LDSP];   // 49,920 B -> 3 blocks/CU

    const int b = blockIdx.x / U;
    int rem = blockIdx.x - b * U;
    int ti = 0;
    while (rem >= S - ti) { rem -= S - ti; ++ti; }   // wave-uniform decode
    const int tj   = ti + rem;
    const bool diag = (ti == tj);
    const int Ai = ti * TILE, Aj = tj * TILE;
    const int rb = b * n;

    const float is0 = inv_std[0], is1 = inv_std[1], is2 = inv_std[2];
    const float mu0 = mu[0],      mu1 = mu[1],      mu2 = mu[2];
    const float l0 = fminf(fmaxf(likerr[0], 0.1f), 1.0f);
    const float l1 = fminf(fmaxf(likerr[1], 0.1f), 1.0f);
    const float l2 = fminf(fmaxf(likerr[2], 0.1f), 1.0f);
    const float nz0 = 1e-4f + l0 * l0;
    const float nz1 = 1e-4f + l1 * l1;
    const float nz2 = 1e-4f + l2 * l2;

    const int lane = threadIdx.x & 63;   // tile column
    const int q    = threadIdx.x >> 6;   // wave id 0..3

    // per-lane column params: loaded ONCE for all 16 rows this wave handles
    const float* xcp = xc + (size_t)(rb + Aj + lane) * 3;
    const float xq0 = xcp[0], xq1 = xcp[1], xq2 = xcp[2];
    const float ec0 = xq0 * is0, ec1 = xq1 * is1, ec2 = xq2 * is2;
    const float mc0 = xq0 * mu0, mc1 = xq1 * mu1, mc2 = xq2 * mu2;

    const size_t row3n = (size_t)3 * n;

    #pragma unroll 4
    for (int it = 0; it < 16; ++it) {
        const int row = q + 4 * it;      // wave-uniform tile row
        const float* xap = xc + (size_t)(rb + Ai + row) * 3;
        const float xa0 = xap[0], xa1 = xap[1], xa2 = xap[2];
        const float ea0 = xa0 * is0, ea1 = xa1 * is1, ea2 = xa2 * is2;
        const float ma0 = xa0 * mu0, ma1 = xa1 * mu1, ma2 = xa2 * mu2;

        float r0 = smk_elem(ea0, ec0, ma0, mc0);
        float r1 = smk_elem(ea1, ec1, ma1, mc1);
        float r2 = smk_elem(ea2, ec2, ma2, mc2);
        if (diag && lane == row) { r0 += nz0; r1 += nz1; r2 += nz2; }

        float* dst = out + (size_t)(rb + Ai + row) * row3n + 3 * (Aj + lane);
        *reinterpret_cast<float3*>(dst) = make_float3(r0, r1, r2);

        if (!diag) {                     // stage for mirror
            float* vp = V + row * LDSP + 3 * lane;
            vp[0] = r0; vp[1] = r1; vp[2] = r2;
        }
    }

    if (!diag) {
        __syncthreads();
        #pragma unroll 4
        for (int it = 0; it < 16; ++it) {
            const int crow = q + 4 * it;             // transposed row (col idx)
            const float* vp = V + lane * LDSP + 3 * crow;
            const float r0 = vp[0], r1 = vp[1], r2 = vp[2];
            float* dst = out + (size_t)(rb + Aj + crow) * row3n + 3 * (Ai + lane);
            *reinterpret_cast<float3*>(dst) = make_float3(r0, r1, r2);
        }
    }
}

// Fallback (R4) for shapes not divisible by TILE
__global__ __launch_bounds__(256) void smk_main(
    const float* __restrict__ xc, const float* __restrict__ mu,
    const float* __restrict__ inv_std, const float* __restrict__ likerr,
    float* __restrict__ out, int n)
{
    const int blk = blockIdx.x;
    const int b   = blk / n;
    const int a   = blk - b * n;
    const int rb  = b * n;

    const float is0 = inv_std[0], is1 = inv_std[1], is2 = inv_std[2];
    const float mu0 = mu[0],      mu1 = mu[1],      mu2 = mu[2];

    const float* xa = xc + (size_t)(rb + a) * 3;
    const float ea0 = xa[0] * is0, ea1 = xa[1] * is1, ea2 = xa[2] * is2;
    const float ma0 = xa[0] * mu0, ma1 = xa[1] * mu1, ma2 = xa[2] * mu2;

    const float l0 = fminf(fmaxf(likerr[0], 0.1f), 1.0f);
    const float l1 = fminf(fmaxf(likerr[1], 0.1f), 1.0f);
    const float l2 = fminf(fmaxf(likerr[2], 0.1f), 1.0f);
    const float nz0 = 1e-4f + l0 * l0;
    const float nz1 = 1e-4f + l1 * l1;
    const float nz2 = 1e-4f + l2 * l2;

    const float* __restrict__ xrow = xc  + (size_t)rb  * 3;
    float*       __restrict__ orow = out + (size_t)blk * 3 * n;

    #pragma unroll 4
    for (int c = threadIdx.x; c < n; c += 256) {
        const float3 xq = *reinterpret_cast<const float3*>(xrow + 3 * c);
        float r0 = smk_elem(ea0, xq.x * is0, ma0, xq.x * mu0);
        float r1 = smk_elem(ea1, xq.y * is1, ma1, xq.y * mu1);
        float r2 = smk_elem(ea2, xq.z * is2, ma2, xq.z * mu2);
        if (c == a) { r0 += nz0; r1 += nz1; r2 += nz2; }
        *reinterpret_cast<float3*>(orow + 3 * c) = make_float3(r0, r1, r2);
    }
}

extern "C" void kernel_launch(void* const* d_in, const int* in_sizes, int n_in,
                              void* d_out, int out_size, void* d_ws, size_t ws_size,
                              hipStream_t stream) {
    const float* xc      = (const float*)d_in[0];
    const float* mu      = (const float*)d_in[1];
    const float* inv_std = (const float*)d_in[2];
    const float* likerr  = (const float*)d_in[3];
    float*       out     = (float*)d_out;

    const int  C = in_sizes[3];                       // nchannel = 3
    const int  D = in_sizes[1] / C;                   // ndim = 1
    const long P = (long)in_sizes[0] / ((long)C * D); // nb*n
    const long n = (long)out_size / (P * C);          // n
    const long nb = P / n;
    (void)n_in; (void)d_ws; (void)ws_size;

    if (n % TILE == 0) {
        const int S = (int)(n / TILE);
        const int U = S * (S + 1) / 2;
        smk_sym<<<dim3((unsigned)(nb * U)), dim3(256), 0, stream>>>(
            xc, mu, inv_std, likerr, out, (int)n, S, U);
    } else {
        smk_main<<<dim3((unsigned)P), dim3(256), 0, stream>>>(
            xc, mu, inv_std, likerr, out, (int)n);
    }
}